// Round 7
// baseline (431.440 us; speedup 1.0000x reference)
//
#include <hip/hip_runtime.h>
#include <math.h>

#define D     768
#define HEADS 12
#define DH    64
#define BATCH 8
#define LSEQ  256
#define MROWS 2048      // BATCH*LSEQ
#define NDICT 16384
#define TOPK  8

typedef _Float16 half_t;
typedef half_t half8 __attribute__((ext_vector_type(8)));
typedef float floatx4 __attribute__((ext_vector_type(4)));

// ---------------- workspace offsets (float-slot units) ----------------
// CLEAN LAYOUT (R6, proven): no two concurrently-live buffers overlap.
#define F_DICT   0u          // gdict_h   16384x768 f16 = 6,291,456 slots (live all run)
#define F_TN     6291456u    // tn_h      2048x768  f16 =   786,432
#define F_LOC    7077888u    // loc_h     2048x768  f16 =   786,432
#define F_WT     7864320u    // wt        8x768x768 f16 = 2,359,296
#define F_BF     10223616u   // bf        6144 f32 (+pad)=     8,192
#define F_TOPI   10231808u   // topi      16384 int      =    16,384
#define F_LP     10248192u   // lp        2048x3072 f16 = 3,145,728
#define F_SIM    13393920u   // sim       2048x16384 f16 = 16,777,216 (dead after topk1)
                             //   dkv [<=16384][1536] f16 reuses F_SIM (serial)
                             //   dd  [4096][768] f32     reuses F_SIM (serial)
#define F_CTX    30171136u   // ctx_ll    2048x768 f16  =   786,432
#define F_D1     30957568u   // Opart     4x2048x768 f16 = 3,145,728 (s0 = ctx_lg)
#define F_CANDV  30957568u   // candv 131,072 f32 — reuses Opart s0 (dead before flash2)
#define F_CANDI  31088640u   // candi 131,072 int — ditto
#define F_ML     34103296u   // ml        4x2048x12x2 f32 = 196,608
#define F_NRM    34299904u   // dnrm      16384 f32
#define F_USED   34316288u   // used      16384 int
#define F_ROWMAP 34332672u   // rowmap    16384 int
#define F_INVMAP 34349056u   // invmap    16384 int
#define F_CNT    34365440u   // cnt       1 int
// high-water = 34,365,441 slots = 137.46 MB  (< 138.6 MB proven in R1)

typedef const __attribute__((address_space(1))) void* gptr_as1;
typedef __attribute__((address_space(3))) void* lptr_as3;
#define GLDS16(gp, lp) __builtin_amdgcn_global_load_lds((gptr_as1)(gp), (lptr_as3)(lp), 16, 0, 0)

// ---------------- helpers ----------------
__device__ __forceinline__ float bsum(float v, float* red) {
  int t = threadIdx.x;
#pragma unroll
  for (int d = 32; d > 0; d >>= 1) v += __shfl_xor(v, d);
  if ((t & 63) == 0) red[t >> 6] = v;
  __syncthreads();
  float r = red[0] + red[1] + red[2] + red[3];
  __syncthreads();   // protect red[] (WAR) for the next call
  return r;
}

// ---------------- fused pre-pass: dict/local norms + 8 weight transposes -------
__global__ __launch_bounds__(256) void k_prep_wt(
    const float* __restrict__ dict, const float* __restrict__ local,
    half_t* __restrict__ gdict_h, float* __restrict__ dnrm,
    half_t* __restrict__ loc_h, half_t* __restrict__ tn_h,
    const float* w0, const float* w1, const float* w2, const float* w3,
    const float* w4, const float* w5, const float* w6, const float* w7,
    const float* b0, const float* b1, const float* b2, const float* b3,
    const float* b4, const float* b5, const float* b6, const float* b7,
    half_t* __restrict__ Wt, float* __restrict__ bfout) {
  __shared__ float red[8];
  __shared__ float tile[32][33];
  int g = blockIdx.x, t = threadIdx.x;
  if (g < NDICT) {
    const float* xr = dict + (size_t)g * D;
    float v0 = xr[t], v1 = xr[t + 256], v2 = xr[t + 512];
    float s = bsum(v0*v0 + v1*v1 + v2*v2, red);
    float n = sqrtf(s), inv = 1.0f / n;
    half_t* yr = gdict_h + (size_t)g * D;
    yr[t] = (half_t)(v0*inv); yr[t+256] = (half_t)(v1*inv); yr[t+512] = (half_t)(v2*inv);
    if (t == 0) dnrm[g] = n;
  } else if (g < NDICT + MROWS) {
    size_t r = g - NDICT;
    const float* xr = local + r * (size_t)D;
    float v0 = xr[t], v1 = xr[t + 256], v2 = xr[t + 512];
    float s = bsum(v0*v0 + v1*v1 + v2*v2, red);
    float inv = 1.0f / sqrtf(s);
    half_t* rr = loc_h + r * (size_t)D;
    half_t* nr = tn_h + r * (size_t)D;
    rr[t] = (half_t)v0;        rr[t+256] = (half_t)v1;        rr[t+512] = (half_t)v2;
    nr[t] = (half_t)(v0*inv);  nr[t+256] = (half_t)(v1*inv);  nr[t+512] = (half_t)(v2*inv);
  } else {
    const float* wsrcs[8] = {w0,w1,w2,w3,w4,w5,w6,w7};
    const float* bsrcs[8] = {b0,b1,b2,b3,b4,b5,b6,b7};
    int id = g - (NDICT + MROWS);
    int z = id / 576, rem = id % 576;
    int by = rem / 24, bx = rem % 24;
    const float* Wsrc = wsrcs[z];
    half_t* dst = Wt + (size_t)z * D * D;
    int tx = t & 31, ty = t >> 5;
    int c0 = bx * 32, r0 = by * 32;
#pragma unroll
    for (int j = 0; j < 4; j++)
      tile[ty + j*8][tx] = Wsrc[(size_t)(r0 + ty + j*8) * D + c0 + tx];
    __syncthreads();
#pragma unroll
    for (int j = 0; j < 4; j++)
      dst[(size_t)(c0 + ty + j*8) * D + r0 + tx] = (half_t)tile[tx][ty + j*8];
    if (bx == 0 && by == 0) {
#pragma unroll
      for (int j = 0; j < 3; j++)
        bfout[z * D + t + j*256] = bsrcs[z][t + j*256];
    }
  }
}

// ---------------- 128x128 fp16 MFMA NT GEMM core (kept for k_gemm_wo) ----------
__device__ __forceinline__ void hgemm_core(
    const half_t* __restrict__ A, const half_t* __restrict__ B,
    const float* __restrict__ bias, const float* __restrict__ dnrm,
    const int* __restrict__ rowmap, void* __restrict__ Cout,
    int N, int K, int outHalf, int bx, int by, int mhalf,
    half_t* As, half_t* Bs) {
  int tid = threadIdx.x;
  int wid = tid >> 6, lane = tid & 63;
  int l16 = lane & 15, quad = lane >> 4;
  int n0 = bx * 128, m0 = by * 128;
  if (mhalf && m0 >= mhalf) { B += (size_t)D * D; if (bias) bias += D; }
  int wm = (wid & 1) * 64, wn = (wid >> 1) * 64;

  int r0  = tid >> 3;
  int cbg = (tid & 7) ^ (r0 & 7);
  const half_t* Aps[4];
#pragma unroll
  for (int i = 0; i < 4; i++) {
    int mm = m0 + r0 + 32*i;
    int mr = rowmap ? rowmap[mm] : mm;
    Aps[i] = A + (size_t)mr * K + cbg * 8;
  }
  const half_t* Bp = B + (size_t)(n0 + r0) * K + cbg * 8;

  floatx4 acc[4][4];
#pragma unroll
  for (int i = 0; i < 4; i++)
#pragma unroll
    for (int j = 0; j < 4; j++) { acc[i][j][0]=0.f; acc[i][j][1]=0.f; acc[i][j][2]=0.f; acc[i][j][3]=0.f; }

  for (int k0 = 0; k0 < K; k0 += 64) {
#pragma unroll
    for (int i = 0; i < 4; i++)
      GLDS16(Aps[i] + k0, As + ((size_t)i*256 + wid*64) * 8);
#pragma unroll
    for (int i = 0; i < 4; i++)
      GLDS16(Bp + k0 + (size_t)i * 32 * K, Bs + ((size_t)i*256 + wid*64) * 8);
    __syncthreads();
#pragma unroll
    for (int ks = 0; ks < 2; ks++) {
      half8 af[4], bf[4];
#pragma unroll
      for (int i = 0; i < 4; i++) {
        int row = wm + i*16 + l16;
        int cb = (quad + ks*4) ^ (row & 7);
        af[i] = *(const half8*)&As[row*64 + cb*8];
      }
#pragma unroll
      for (int j = 0; j < 4; j++) {
        int row = wn + j*16 + l16;
        int cb = (quad + ks*4) ^ (row & 7);
        bf[j] = *(const half8*)&Bs[row*64 + cb*8];
      }
#pragma unroll
      for (int i = 0; i < 4; i++)
#pragma unroll
        for (int j = 0; j < 4; j++)
          acc[i][j] = __builtin_amdgcn_mfma_f32_16x16x32_f16(af[i], bf[j], acc[i][j], 0, 0, 0);
    }
    __syncthreads();
  }

  float bcol[4];
#pragma unroll
  for (int j = 0; j < 4; j++) bcol[j] = bias ? bias[n0 + wn + j*16 + l16] : 0.f;
  if (outHalf) {
    half_t* C = (half_t*)Cout;
#pragma unroll
    for (int i = 0; i < 4; i++)
#pragma unroll
      for (int r = 0; r < 4; r++) {
        int grow = m0 + wm + i*16 + quad*4 + r;
        float sc = dnrm ? dnrm[rowmap ? rowmap[grow] : grow] : 1.0f;
#pragma unroll
        for (int j = 0; j < 4; j++)
          C[(size_t)grow * N + n0 + wn + j*16 + l16] = (half_t)(acc[i][j][r] * sc + bcol[j]);
      }
  } else {
    float* C = (float*)Cout;
#pragma unroll
    for (int i = 0; i < 4; i++)
#pragma unroll
      for (int r = 0; r < 4; r++) {
        int grow = m0 + wm + i*16 + quad*4 + r;
        float sc = dnrm ? dnrm[rowmap ? rowmap[grow] : grow] : 1.0f;
#pragma unroll
        for (int j = 0; j < 4; j++)
          C[(size_t)grow * N + n0 + wn + j*16 + l16] = acc[i][j][r] * sc + bcol[j];
      }
  }
}

// ---------------- 256x256 8-wave 4-phase counted-vmcnt fp16 NT GEMM core -------
// T3+T4+T5 schedule on the R6-proven datapath. Per K-tile: 4 phases of
// {ds-read quadrant + stage one half-tile -> vmcnt(4) -> barrier ->
//  setprio(1) + 16 MFMA + setprio(0) -> barrier}. vmcnt never drains to 0 in
// the main loop: queue invariant at each P1 entry = [Bh1(t)x2, Ah1(t)x2].
// P1 vmcnt(4) retires Bh1(t) (needed by P2); P2 retires Ah1(t) (needed by P3);
// P3 no wait (P4 re-reads resident Bh0(t)); P4 retires Ah0,Bh0(t+1) (needed
// by next P1). Tail drains 2 -> 0. Same fragment/XOR-8/epilogue as R6.
__device__ __forceinline__ void hgemm256_core(
    const half_t* __restrict__ A, const half_t* __restrict__ B,
    const float* __restrict__ bias, const float* __restrict__ dnrm,
    const int* __restrict__ rowmap, half_t* __restrict__ C,
    int N, int K, int bx, int by,
    half_t* As0, half_t* As1, half_t* Bs0, half_t* Bs1) {
  const int tid = threadIdx.x;
  const int wid = tid >> 6, lane = tid & 63;
  const int l16 = lane & 15, quad = lane >> 4;
  const int m0 = by * 256, n0 = bx * 256;

  // staging sources: per-lane addr, pre-swizzled colgroup (XOR-8)
  const int r0 = tid >> 3;                    // [0,64)
  const int cg = (tid & 7) ^ (r0 & 7);        // (i*64)&7 == 0, same for all i
  const half_t* Aps[4]; const half_t* Bps[4];
#pragma unroll
  for (int i = 0; i < 4; i++) {
    int mm = m0 + r0 + i * 64;
    int mr = rowmap ? rowmap[mm] : mm;
    Aps[i] = A + (size_t)mr * K + cg * 8;
    Bps[i] = B + (size_t)(n0 + r0 + i * 64) * K + cg * 8;
  }

  // LDS read geometry (row stride 64 halfs; swizzled colgroup read)
  const int arow = (wid & 3) * 32 + l16;      // row in 128-row A quadrant
  const int brow = (wid >> 2) * 64 + l16;     // row in 128-row B quadrant
  const int cb0 = (quad ^ (l16 & 7)) * 8;
  const int cb1 = ((quad + 4) ^ (l16 & 7)) * 8;

  floatx4 acc[4][2][4];                        // [quadrant][mi][ni]
#pragma unroll
  for (int q = 0; q < 4; q++)
#pragma unroll
    for (int mi = 0; mi < 2; mi++)
#pragma unroll
      for (int ni = 0; ni < 4; ni++) {
        acc[q][mi][ni][0] = 0.f; acc[q][mi][ni][1] = 0.f;
        acc[q][mi][ni][2] = 0.f; acc[q][mi][ni][3] = 0.f;
      }
  half8 af[2][2], bf[4][2];

#define STG_A(dst, i, kn) GLDS16(Aps[i] + (kn), (dst) + ((i)*512 + wid*64) * 8)
#define STG_B(dst, i, kn) GLDS16(Bps[i] + (kn), (dst) + ((i)*512 + wid*64) * 8)
#define LDA(qm) { const int rb_ = (qm)*8192 + arow*64; \
    af[0][0] = *(const half8*)&Ar[rb_ + cb0];        af[0][1] = *(const half8*)&Ar[rb_ + cb1]; \
    af[1][0] = *(const half8*)&Ar[rb_ + 1024 + cb0]; af[1][1] = *(const half8*)&Ar[rb_ + 1024 + cb1]; }
#define LDB(qn) { const int rb_ = (qn)*8192 + brow*64; \
    bf[0][0] = *(const half8*)&Br[rb_ + cb0];        bf[0][1] = *(const half8*)&Br[rb_ + cb1]; \
    bf[1][0] = *(const half8*)&Br[rb_ + 1024 + cb0]; bf[1][1] = *(const half8*)&Br[rb_ + 1024 + cb1]; \
    bf[2][0] = *(const half8*)&Br[rb_ + 2048 + cb0]; bf[2][1] = *(const half8*)&Br[rb_ + 2048 + cb1]; \
    bf[3][0] = *(const half8*)&Br[rb_ + 3072 + cb0]; bf[3][1] = *(const half8*)&Br[rb_ + 3072 + cb1]; }
#define MM(q) { _Pragma("unroll") for (int mi = 0; mi < 2; mi++) { \
    _Pragma("unroll") for (int ni = 0; ni < 4; ni++) { \
      acc[q][mi][ni] = __builtin_amdgcn_mfma_f32_16x16x32_f16(af[mi][0], bf[ni][0], acc[q][mi][ni], 0, 0, 0); \
      acc[q][mi][ni] = __builtin_amdgcn_mfma_f32_16x16x32_f16(af[mi][1], bf[ni][1], acc[q][mi][ni], 0, 0, 0); } } }
#define VMC(n) asm volatile("s_waitcnt vmcnt(" #n ")" ::: "memory")
#define SBAR() __builtin_amdgcn_s_barrier()
#define SCHED0() __builtin_amdgcn_sched_barrier(0)

  // prologue: stage K-tile 0 into buf0 in half-tile order Ah0,Bh0,Bh1,Ah1
  STG_A(As0, 0, 0); STG_A(As0, 1, 0);
  STG_B(Bs0, 0, 0); STG_B(Bs0, 1, 0);
  STG_B(Bs0, 2, 0); STG_B(Bs0, 3, 0);
  STG_A(As0, 2, 0); STG_A(As0, 3, 0);
  VMC(4); SBAR();                 // Ah0(0), Bh0(0) landed for all waves

  half_t* Ar = As0; half_t* Aw = As1;
  half_t* Br = Bs0; half_t* Bw = Bs1;

  const int NT = K >> 6;          // 12 for K=768
  for (int t = 0; t < NT - 1; ++t) {
    const int kn = (t + 1) * 64;
    // ---- P1: Q(0,0); stage Ah0(t+1); vmcnt(4) retires Bh1(t) for P2 ----
    SCHED0();
    LDA(0); LDB(0);
    STG_A(Aw, 0, kn); STG_A(Aw, 1, kn);
    VMC(4); SBAR(); SCHED0();
    __builtin_amdgcn_s_setprio(1); MM(0); __builtin_amdgcn_s_setprio(0);
    SBAR();
    // ---- P2: Q(0,1); stage Bh0(t+1); vmcnt(4) retires Ah1(t) for P3 ----
    SCHED0();
    LDB(1);
    STG_B(Bw, 0, kn); STG_B(Bw, 1, kn);
    VMC(4); SBAR(); SCHED0();
    __builtin_amdgcn_s_setprio(1); MM(1); __builtin_amdgcn_s_setprio(0);
    SBAR();
    // ---- P3: Q(1,1); stage Bh1(t+1); no wait (P4 re-reads resident Bh0) ----
    SCHED0();
    LDA(1);
    STG_B(Bw, 2, kn); STG_B(Bw, 3, kn);
    SBAR(); SCHED0();
    __builtin_amdgcn_s_setprio(1); MM(2); __builtin_amdgcn_s_setprio(0);
    SBAR();
    // ---- P4: Q(1,0); stage Ah1(t+1); vmcnt(4) retires Ah0,Bh0(t+1) ----
    SCHED0();
    LDB(0);
    STG_A(Aw, 2, kn); STG_A(Aw, 3, kn);
    VMC(4); SBAR(); SCHED0();
    __builtin_amdgcn_s_setprio(1); MM(3); __builtin_amdgcn_s_setprio(0);
    SBAR();
    half_t* tp = Ar; Ar = Aw; Aw = tp;
    tp = Br; Br = Bw; Bw = tp;
  }
  // ---- tail K-tile (no staging; drain by count: 4 -> 2 -> 0) ----
  SCHED0();
  LDA(0); LDB(0);
  VMC(2); SBAR(); SCHED0();       // Bh1(last) landed
  __builtin_amdgcn_s_setprio(1); MM(0); __builtin_amdgcn_s_setprio(0);
  SBAR();
  SCHED0();
  LDB(1);
  VMC(0); SBAR(); SCHED0();       // Ah1(last) landed; queue empty
  __builtin_amdgcn_s_setprio(1); MM(1); __builtin_amdgcn_s_setprio(0);
  SBAR();
  SCHED0();
  LDA(1);
  SBAR(); SCHED0();
  __builtin_amdgcn_s_setprio(1); MM(2); __builtin_amdgcn_s_setprio(0);
  SBAR();
  SCHED0();
  LDB(0);
  __builtin_amdgcn_s_setprio(1); MM(3); __builtin_amdgcn_s_setprio(0);

  // ---- epilogue ----
  float bcol[2][4];
#pragma unroll
  for (int qn = 0; qn < 2; qn++)
#pragma unroll
    for (int ni = 0; ni < 4; ni++)
      bcol[qn][ni] = bias ? bias[n0 + qn*128 + (wid >> 2)*64 + ni*16 + l16] : 0.f;
#pragma unroll
  for (int q = 0; q < 4; q++) {
    const int qm = q >> 1;                       // 0,0,1,1
    const int qn = (q == 1 || q == 2) ? 1 : 0;   // 0,1,1,0
#pragma unroll
    for (int mi = 0; mi < 2; mi++)
#pragma unroll
      for (int r = 0; r < 4; r++) {
        int grow = m0 + qm*128 + (wid & 3)*32 + mi*16 + quad*4 + r;
        float sc = dnrm ? dnrm[rowmap ? rowmap[grow] : grow] : 1.0f;
#pragma unroll
        for (int ni = 0; ni < 4; ni++)
          C[(size_t)grow * N + n0 + qn*128 + (wid >> 2)*64 + ni*16 + l16] =
              (half_t)(acc[q][mi][ni][r] * sc + bcol[qn][ni]);
      }
  }
#undef STG_A
#undef STG_B
#undef LDA
#undef LDB
#undef MM
#undef VMC
#undef SBAR
#undef SCHED0
}

// ---------------- merged sim (512 blocks) + lp (96 blocks), 256^2 tiles -------
__global__ __launch_bounds__(512) void k_gemm_simlp(
    const half_t* __restrict__ tn, const half_t* __restrict__ gd,
    half_t* __restrict__ sim,
    const half_t* __restrict__ loc, const half_t* __restrict__ wt0,
    const float* __restrict__ bf0, half_t* __restrict__ lp) {
  __shared__ half_t As[2][256*64];
  __shared__ half_t Bs[2][256*64];
  int gid = blockIdx.x;
  int swz = (gid & 7) * 76 + (gid >> 3);   // 608 = 8*76, bijective XCD chunking
  if (swz < 512) {       // sim: logical grid 64 x 8, 8x8 panel swizzle
    int bx = (swz & 7) + ((swz >> 3) >> 3) * 8;
    int by = (swz >> 3) & 7;
    hgemm256_core(tn, gd, nullptr, nullptr, nullptr, sim, NDICT, D, bx, by,
                  As[0], As[1], Bs[0], Bs[1]);
  } else {               // lp: logical grid 12 x 8
    int rel = swz - 512;
    int bx = rel >> 3;
    int by = rel & 7;
    hgemm256_core(loc, wt0, bf0, nullptr, nullptr, lp, 3072, D, bx, by,
                  As[0], As[1], Bs[0], Bs[1]);
  }
}

// ---------------- dkv over compacted dict rows (early exit past count) ---------
__global__ __launch_bounds__(512) void k_gemm_dkv(
    const half_t* __restrict__ gd, const half_t* __restrict__ wt4,
    const float* __restrict__ bf4, const float* __restrict__ dnrm,
    const int* __restrict__ rowmap, const int* __restrict__ cnt,
    half_t* __restrict__ dkv) {
  __shared__ half_t As[2][256*64];
  __shared__ half_t Bs[2][256*64];
  int mceil = (*cnt + 255) & ~255;
  if ((int)blockIdx.y * 256 >= mceil) return;
  hgemm256_core(gd, wt4, bf4, dnrm, rowmap, dkv, 1536, D,
                blockIdx.x, blockIdx.y, As[0], As[1], Bs[0], Bs[1]);
}

// ---------------- fused output projection (ll|lg via mhalf), fp32 out ----------
__global__ __launch_bounds__(256) void k_gemm_wo(
    const half_t* __restrict__ ctx, const half_t* __restrict__ wt6,
    const float* __restrict__ bf6, float* __restrict__ dd) {
  __shared__ half_t As[128*64];
  __shared__ half_t Bs[128*64];
  hgemm_core(ctx, wt6, bf6, nullptr, nullptr, dd, D, D, 0, blockIdx.x, blockIdx.y, MROWS, As, Bs);
}

// ---------------- top-k stage 1: tournament argmax, wave per (row, segment) ----
__global__ __launch_bounds__(256) void k_topk1(const half_t* __restrict__ sim,
                                               float* __restrict__ candv,
                                               int* __restrict__ candi,
                                               int* __restrict__ used,
                                               int* __restrict__ rowmap,
                                               int* __restrict__ cnt) {
  int t = threadIdx.x;
  if (t < 4) used[blockIdx.x * 4 + t] = 0;
  else if (t < 8) rowmap[blockIdx.x * 4 + t - 4] = 0;
  if (blockIdx.x == 0 && t == 8) *cnt = 0;

  int gw = blockIdx.x * 4 + (t >> 6);
  int lane = t & 63;
  int row = gw >> 3, seg = gw & 7;
  int cbase = seg * 2048;
  const half_t* p = sim + (size_t)row * NDICT + cbase;

  float v[32];
#pragma unroll
  for (int i = 0; i < 4; i++) {
    half8 h = *(const half8*)(p + i*512 + lane*8);
#pragma unroll
    for (int j = 0; j < 8; j++) v[i*8 + j] = (float)h[j];
  }
  float m = v[0]; int pos = 0;
#pragma unroll
  for (int i = 1; i < 32; i++) { if (v[i] > m) { m = v[i]; pos = i; } }

  for (int it = 0; it < 8; it++) {
    int gidx = cbase + (pos >> 3) * 512 + lane * 8 + (pos & 7);
    float bv = m; int bi = gidx;
#pragma unroll
    for (int d2 = 1; d2 < 64; d2 <<= 1) {
      float ov = __shfl_xor(bv, d2); int oi = __shfl_xor(bi, d2);
      if (ov > bv || (ov == bv && oi < bi)) { bv = ov; bi = oi; }
    }
    if (lane == 0) {
      size_t base = (size_t)row * 64 + seg * 8 + it;
      candv[base] = bv; candi[base] = bi;
    }
    if (bi == gidx) {
      v[pos] = -INFINITY;
      m = v[0]; pos = 0;
#pragma unroll
      for (int i = 1; i < 32; i++) { if (v[i] > m) { m = v[i]; pos = i; } }
    }
  }
}

// ---------------- top-k stage 2: wave per row over 64 candidates ----------------
// (k_mark fused in: lane0 marks used[] while emitting topi)
__global__ __launch_bounds__(256) void k_topk2(const float* __restrict__ candv,
                                               const int* __restrict__ candi,
                                               int* __restrict__ topi,
                                               int* __restrict__ used) {
  int row = blockIdx.x * 4 + (threadIdx.x >> 6);
  int lane = threadIdx.x & 63;
  float v = candv[(size_t)row * 64 + lane];
  int id = candi[(size_t)row * 64 + lane];
#pragma unroll
  for (int it = 0; it < 8; it++) {
    float bv = v; int bi = id;
#pragma unroll
    for (int d2 = 1; d2 < 64; d2 <<= 1) {
      float ov = __shfl_xor(bv, d2); int oi = __shfl_xor(bi, d2);
      if (ov > bv || (ov == bv && oi < bi)) { bv = ov; bi = oi; }
    }
    if (lane == 0) { topi[row * 8 + it] = bi; used[bi] = 1; }
    if (id == bi) { v = -INFINITY; id = 0x7FFFFFFF; }
  }
}

// ---------------- dedup: compact used dict rows -> remap topi ----------
__global__ __launch_bounds__(256) void k_cmp(const int* __restrict__ used,
                                             int* __restrict__ rowmap,
                                             int* __restrict__ invmap,
                                             int* __restrict__ cnt) {
  int i = blockIdx.x * 256 + threadIdx.x;
  if (used[i]) { int s = atomicAdd(cnt, 1); rowmap[s] = i; invmap[i] = s; }
}
__global__ __launch_bounds__(256) void k_remap(int* __restrict__ topi,
                                               const int* __restrict__ invmap) {
  int i = blockIdx.x * 256 + threadIdx.x;
  topi[i] = invmap[topi[i]];
}

// ---------------- combined fp16 MFMA flash: lg (K-split ns=4) + ll (ns=1) ------
__global__ __launch_bounds__(256) void k_flash2(
    const half_t* __restrict__ lp, const half_t* __restrict__ dkv,
    const int* __restrict__ topi_,
    half_t* __restrict__ ctx_ll, half_t* __restrict__ Opart, float* __restrict__ ml) {
  __shared__ half_t Ks[64][72];
  __shared__ half_t Vt[64][72];
  __shared__ half_t Ps[4][16][72];

  int tid = threadIdx.x;
  int wid = tid >> 6;
  int lane = tid & 63;
  int l16 = lane & 15, quad = lane >> 4;

  const half_t *Q, *K, *V; const int* kidx; half_t* Out;
  int qS, kvS, Sk, ns, rel;
  if (blockIdx.x < BATCH*HEADS*4*4) {     // lg
    rel = blockIdx.x;
    Q = lp + 2304; qS = 3072; K = dkv; V = dkv + 768; kvS = 1536;
    kidx = topi_; Sk = LSEQ*TOPK; ns = 4; Out = nullptr;
  } else {                                 // ll
    rel = blockIdx.x - BATCH*HEADS*4*4;
    Q = lp; qS = 3072; K = lp + 768; V = lp + 1536; kvS = 3072;
    kidx = nullptr; Sk = LSEQ; ns = 1; Out = ctx_ll;
  }

  int sp = rel % ns;
  int rest = rel / ns;
  int qt = rest & 3;
  int h  = (rest >> 2) % HEADS;
  int bb = rest / (4 * HEADS);
  int q0 = qt * 64 + wid * 16;
  int sLen = Sk / ns, s0 = sp * sLen;

  const float SCL = 0.125f * 1.4426950408889634f;
  const half_t* qrow = Q + (size_t)(bb * LSEQ + q0 + l16) * qS + h * DH;
  half8 aq0 = *(const half8*)(qrow + quad*8);
  half8 aq1 = *(const half8*)(qrow + 32 + quad*8);

  floatx4 o[4];
#pragma unroll
  for (int nt = 0; nt < 4; nt++) { o[nt][0]=0.f; o[nt][1]=0.f; o[nt][2]=0.f; o[nt][3]=0.f; }
  float mreg[4] = {-INFINITY, -INFINITY, -INFINITY, -INFINITY};
  float lreg[4] = {0.f, 0.f, 0.f, 0.f};

  for (int k0 = s0; k0 < s0 + sLen; k0 += 64) {
    {
      int row = tid >> 2, cg = tid & 3;
      int key = k0 + row;
      size_t rowid = kidx ? (size_t)kidx[(size_t)bb * Sk + key]
                          : (size_t)(bb * LSEQ + key);
      const half_t* kb = K + rowid * (size_t)kvS + h * DH + cg * 16;
      const half_t* vb = V + rowid * (size_t)kvS + h * DH + cg * 16;
      *(half8*)&Ks[row][cg*16]     = *(const half8*)kb;
      *(half8*)&Ks[row][cg*16 + 8] = *(const half8*)(kb + 8);
      half8 v0 = *(const half8*)vb, v1 = *(const half8*)(vb + 8);
#pragma unroll
      for (int jj = 0; jj < 8; jj++) { Vt[cg*16 + jj][row] = v0[jj]; Vt[cg*16 + 8 + jj][row] = v1[jj]; }
    }
    __syncthreads();

    floatx4 c[4];
#pragma unroll
    for (int nt = 0; nt < 4; nt++) {
      half8 b0 = *(const half8*)&Ks[nt*16 + l16][quad*8];
      half8 b1 = *(const half8*)&Ks[nt*16 + l16][32 + quad*8];
      floatx4 z; z[0]=0.f; z[1]=0.f; z[2]=0.f; z[3]=0.f;
      z = __builtin_amdgcn_mfma_f32_16x16x32_f16(aq0, b0, z, 0, 0, 0);
      z = __builtin_amdgcn_mfma_f32_16x16x32_f16(aq1, b1, z, 0, 0, 0);
      c[nt] = z;
    }

    float alpha[4];
#pragma unroll
    for (int r = 0; r < 4; r++) {
      float mx = fmaxf(fmaxf(c[0][r], c[1][r]), fmaxf(c[2][r], c[3][r]));
      mx = fmaxf(mx, __shfl_xor(mx, 1));
      mx = fmaxf(mx, __shfl_xor(mx, 2));
      mx = fmaxf(mx, __shfl_xor(mx, 4));
      mx = fmaxf(mx, __shfl_xor(mx, 8));
      float mn = fmaxf(mreg[r], mx);
      float al = __builtin_amdgcn_exp2f((mreg[r] - mn) * SCL);
      float ps = 0.f;
#pragma unroll
      for (int nt = 0; nt < 4; nt++) {
        float p = __builtin_amdgcn_exp2f((c[nt][r] - mn) * SCL);
        c[nt][r] = p; ps += p;
      }
      ps += __shfl_xor(ps, 1);
      ps += __shfl_xor(ps, 2);
      ps += __shfl_xor(ps, 4);
      ps += __shfl_xor(ps, 8);
      mreg[r] = mn; lreg[r] = lreg[r] * al + ps; alpha[r] = al;
    }

#pragma unroll
    for (int nt = 0; nt < 4; nt++)
#pragma unroll
      for (int r = 0; r < 4; r++)
        Ps[wid][quad*4 + r][nt*16 + l16] = (half_t)c[nt][r];
    half8 p0 = *(const half8*)&Ps[wid][l16][quad*8];
    half8 p1 = *(const half8*)&Ps[wid][l16][32 + quad*8];

#pragma unroll
    for (int nt = 0; nt < 4; nt++)
#pragma unroll
      for (int r = 0; r < 4; r++) o[nt][r] *= alpha[r];
#pragma unroll
    for (int nt = 0; nt < 4; nt++) {
      half8 v0 = *(const half8*)&Vt[nt*16 + l16][quad*8];
      half8 v1 = *(const half8*)&Vt[nt*16 + l16][32 + quad*8];
      o[nt] = __builtin_amdgcn_mfma_f32_16x16x32_f16(p0, v0, o[nt], 0, 0, 0);
      o[nt] = __builtin_amdgcn_mfma_f32_16x16x32_f16(p1, v1, o[nt], 0, 0, 0);
    }
    __syncthreads();
  }

  if (ns == 1) {
    half_t* ob = Out + (size_t)(bb * LSEQ + q0 + quad*4) * D + h * DH;
#pragma unroll
    for (int r = 0; r < 4; r++) {
      float inv = 1.0f / lreg[r];
#pragma unroll
      for (int nt = 0; nt < 4; nt++)
        ob[(size_t)r * D + nt*16 + l16] = (half_t)(o[nt][r] * inv);
    }
  } else {
    size_t rbase = (size_t)sp * MROWS + bb * LSEQ + q0 + quad*4;
    half_t* ob = Opart + rbase * D + h * DH;
#pragma unroll
    for (int r = 0; r < 4; r++) {
      float inv = 1.0f / lreg[r];
#pragma unroll
      for (int nt = 0; nt < 4; nt++)
        ob[(size_t)r * D + nt*16 + l16] = (half_t)(o[nt][r] * inv);
    }
    if (l16 == 0) {
#pragma unroll
      for (int r = 0; r < 4; r++) {
        size_t mi = ((rbase + r) * HEADS + h) * 2;
        ml[mi] = mreg[r]; ml[mi + 1] = lreg[r];
      }
    }
  }
}

// ---------------- combine K-split partials (in-place: ctx == Opart s0) ---------
__global__ __launch_bounds__(256) void k_comb(const half_t* __restrict__ Op,
                                              const float* __restrict__ ml,
                                              half_t* __restrict__ ctx) {
  int r = blockIdx.x, t = threadIdx.x;
  const float SCL = 0.125f * 1.4426950408889634f;
#pragma unroll
  for (int i = 0; i < 3; i++) {
    int col = t + i*256;
    int h = col >> 6;
    float m[4], l[4];
    float ms = -INFINITY;
#pragma unroll
    for (int s = 0; s < 4; s++) {
      size_t mi = (((size_t)s * MROWS + r) * HEADS + h) * 2;
      m[s] = ml[mi]; l[s] = ml[mi + 1];
      ms = fmaxf(ms, m[s]);
    }
    float den = 0.f, num = 0.f;
#pragma unroll
    for (int s = 0; s < 4; s++) {
      float w = __builtin_amdgcn_exp2f((m[s] - ms) * SCL) * l[s];
      den += w;
      num += w * (float)Op[((size_t)s * MROWS + r) * D + col];
    }
    ctx[(size_t)r * D + col] = (half_t)(num / den);
  }
}

// ---------------- fused tail: LN(ll+loc), LN(lg+loc), LN(sum), sigmoid gate ----
__global__ __launch_bounds__(256) void k_lngate3(
    const float* __restrict__ dd, const float* __restrict__ loc,
    const float* __restrict__ llg, const float* __restrict__ llb,
    const float* __restrict__ lgg, const float* __restrict__ lgb,
    const float* __restrict__ lng, const float* __restrict__ lnb,
    const float* __restrict__ aw, const float* __restrict__ ow,
    const float* __restrict__ ab, const float* __restrict__ orb,
    float* __restrict__ y) {
  __shared__ float red[8];
  size_t r = blockIdx.x; int t = threadIdx.x;
  const float* ar = dd + r*(size_t)D;                    // ll dense
  const float* br = dd + ((size_t)MROWS + r)*(size_t)D;  // lg dense
  const float* lcl = loc + r*(size_t)D;
  float l0 = lcl[t], l1 = lcl[t+256], l2 = lcl[t+512];

  float a0 = ar[t]+l0, a1 = ar[t+256]+l1, a2 = ar[t+512]+l2;
  float mu = bsum(a0+a1+a2, red) * (1.0f/768.0f);
  float d0 = a0-mu, d1 = a1-mu, d2 = a2-mu;
  float var = bsum(d0*d0 + d1*d1 + d2*d2, red) * (1.0f/768.0f);
  float rstd = rsqrtf(var + 1e-12f);
  float x0 = d0*rstd*llg[t]     + llb[t];
  float x1 = d1*rstd*llg[t+256] + llb[t+256];
  float x2 = d2*rstd*llg[t+512] + llb[t+512];

  float b0 = br[t]+l0, b1 = br[t+256]+l1, b2 = br[t+512]+l2;
  mu = bsum(b0+b1+b2, red) * (1.0f/768.0f);
  d0 = b0-mu; d1 = b1-mu; d2 = b2-mu;
  var = bsum(d0*d0 + d1*d1 + d2*d2, red) * (1.0f/768.0f);
  rstd = rsqrtf(var + 1e-12f);
  x0 += d0*rstd*lgg[t]     + lgb[t];
  x1 += d1*rstd*lgg[t+256] + lgb[t+256];
  x2 += d2*rstd*lgg[t+512] + lgb[t+512];

  mu = bsum(x0+x1+x2, red) * (1.0f/768.0f);
  d0 = x0-mu; d1 = x1-mu; d2 = x2-mu;
  var = bsum(d0*d0 + d1*d1 + d2*d2, red) * (1.0f/768.0f);
  rstd = rsqrtf(var + 1e-12f);
  float o0 = d0*rstd*lng[t]     + lnb[t];
  float o1 = d1*rstd*lng[t+256] + lnb[t+256];
  float o2 = d2*rstd*lng[t+512] + lnb[t+512];

  float s = o0*aw[t] + l0*ow[t]
          + o1*aw[t+256] + l1*ow[t+256]
          + o2*aw[t+512] + l2*ow[t+512];
  float z = bsum(s, red) + ab[0] + orb[0];
  float w = 1.0f / (1.0f + __expf(-z));
  float* yr = y + r*(size_t)D;
  yr[t]     = w*o0 + (1.f-w)*l0;
  yr[t+256] = w*o1 + (1.f-w)*l1;
  yr[t+512] = w*o2 + (1.f-w)*l2;
}

extern "C" void kernel_launch(void* const* d_in, const int* in_sizes, int n_in,
                              void* d_out, int out_size, void* d_ws, size_t ws_size,
                              hipStream_t stream) {
  (void)in_sizes; (void)n_in; (void)out_size; (void)ws_size;
  const float* local = (const float*)d_in[0];
  const float* dict  = (const float*)d_in[1];
  const float* ll_g  = (const float*)d_in[10];
  const float* ll_b  = (const float*)d_in[11];
  const float* lg_g  = (const float*)d_in[20];
  const float* lg_b  = (const float*)d_in[21];
  const float* ln_g  = (const float*)d_in[22];
  const float* ln_b  = (const float*)d_in[23];
  const float* aug_w = (const float*)d_in[24];
  const float* ori_w = (const float*)d_in[25];
  const float* aug_b = (const float*)d_in[26];
  const float* ori_b = (const float*)d_in[27];

  float* W = (float*)d_ws;
  half_t* gdict_h = (half_t*)(W + F_DICT);
  half_t* tn_h    = (half_t*)(W + F_TN);
  half_t* loc_h   = (half_t*)(W + F_LOC);
  half_t* wt      = (half_t*)(W + F_WT);
  float*  bf      = W + F_BF;
  int*    topi    = (int*)(W + F_TOPI);
  half_t* lp      = (half_t*)(W + F_LP);
  half_t* sim_h   = (half_t*)(W + F_SIM);    // dead after topk1
  half_t* dkv     = (half_t*)(W + F_SIM);    // reuses sim region (serial)
  float*  dd      = W + F_SIM;               // reuses dkv region (serial)
  half_t* ctx_ll  = (half_t*)(W + F_CTX);
  half_t* ctx_lg  = (half_t*)(W + F_D1);     // = Opart s0 (in-place combine)
  half_t* Opart   = (half_t*)(W + F_D1);
  float*  candv   = W + F_CANDV;             // reuses Opart s0 (dead before flash2)
  int*    candi   = (int*)(W + F_CANDI);
  float*  ml      = W + F_ML;
  float*  dnrm    = W + F_NRM;
  int*    used    = (int*)(W + F_USED);
  int*    rowmap  = (int*)(W + F_ROWMAP);
  int*    invmap  = (int*)(W + F_INVMAP);
  int*    cnt     = (int*)(W + F_CNT);

  dim3 blk(256);
  dim3 blk5(512);
  const size_t WS = (size_t)D * D;

  // --- fused pre-pass: norms + weight transposes + bias concat ---
  k_prep_wt<<<NDICT + MROWS + 4608, blk, 0, stream>>>(
      dict, local, gdict_h, dnrm, loc_h, tn_h,
      (const float*)d_in[2], (const float*)d_in[3], (const float*)d_in[4],
      (const float*)d_in[12], (const float*)d_in[13], (const float*)d_in[14],
      (const float*)d_in[5], (const float*)d_in[15],
      (const float*)d_in[6], (const float*)d_in[7], (const float*)d_in[8],
      (const float*)d_in[16], (const float*)d_in[17], (const float*)d_in[18],
      (const float*)d_in[9], (const float*)d_in[19], wt, bf);

  // --- sim + lp in one launch (256^2 8-wave 4-phase counted-vmcnt core) ---
  k_gemm_simlp<<<512 + 96, blk5, 0, stream>>>(tn_h, gdict_h, sim_h,
                                              loc_h, wt + 0*WS, bf + 0, lp);

  // --- two-stage top-8 + dict dedup (mark fused in topk2) ---
  k_topk1<<<MROWS*8/4, blk, 0, stream>>>(sim_h, candv, candi, used, rowmap, cnt);
  k_topk2<<<MROWS/4, blk, 0, stream>>>(candv, candi, topi, used);
  k_cmp<<<64, blk, 0, stream>>>(used, rowmap, invmap, cnt);
  k_remap<<<64, blk, 0, stream>>>(topi, invmap);

  // --- dkv over compact dict rows (dict @ w = diag(||d||) * (dnorm @ w)) ---
  k_gemm_dkv<<<dim3(6, 64), blk5, 0, stream>>>(
      gdict_h, wt + 4*WS, bf + 3072, dnrm, rowmap, cnt, dkv);

  // --- combined flash: lg (ns=4 gather, compact indices) + ll (self) ---
  k_flash2<<<dim3(BATCH*HEADS*4*4 + BATCH*HEADS*4), blk, 0, stream>>>(
      lp, dkv, topi, ctx_ll, Opart, ml);
  k_comb<<<MROWS, blk, 0, stream>>>(Opart, ml, ctx_lg);

  // --- fused output projection: [ctx_ll; ctx_lg] @ {wt6|wt7} -> dd fp32 ---
  k_gemm_wo<<<dim3(6, 32), blk, 0, stream>>>(ctx_ll, wt + 6*WS, bf + 4608, dd);

  // --- fused 3-LN + gate tail ---
  k_lngate3<<<MROWS, blk, 0, stream>>>(dd, local,
      ll_g, ll_b, lg_g, lg_b, ln_g, ln_b,
      aug_w, ori_w, aug_b, ori_b, (float*)d_out);
}

// Round 8
// 420.090 us; speedup vs baseline: 1.0270x; 1.0270x over previous
//
#include <hip/hip_runtime.h>
#include <math.h>

#define D     768
#define HEADS 12
#define DH    64
#define BATCH 8
#define LSEQ  256
#define MROWS 2048      // BATCH*LSEQ
#define NDICT 16384
#define TOPK  8

typedef _Float16 half_t;
typedef half_t half8 __attribute__((ext_vector_type(8)));
typedef half_t half4v __attribute__((ext_vector_type(4)));
typedef float floatx4 __attribute__((ext_vector_type(4)));

// ---------------- workspace offsets (float-slot units) ----------------
// CLEAN LAYOUT (R6, proven): no two concurrently-live buffers overlap.
#define F_DICT   0u          // gdict_h   16384x768 f16 = 6,291,456 slots (live all run)
#define F_TN     6291456u    // tn_h      2048x768  f16 =   786,432
#define F_LOC    7077888u    // loc_h     2048x768  f16 =   786,432
#define F_WT     7864320u    // wt        8x768x768 f16 = 2,359,296
#define F_BF     10223616u   // bf        6144 f32 (+pad)=     8,192
#define F_TOPI   10231808u   // topi      16384 int      =    16,384
#define F_LP     10248192u   // lp        2048x3072 f16 = 3,145,728
#define F_SIM    13393920u   // sim       2048x16384 f16 = 16,777,216 (dead after topk1)
                             //   dkv [<=16384][1536] f16 reuses F_SIM (serial)
                             //   dd  [4096][768] f32     reuses F_SIM (serial)
#define F_CTX    30171136u   // ctx_ll    2048x768 f16  =   786,432
#define F_D1     30957568u   // Opart     4x2048x768 f16 = 3,145,728 (s0 = ctx_lg)
#define F_CANDV  30957568u   // candv 131,072 f32 — reuses Opart s0 (dead before flash2)
#define F_CANDI  31088640u   // candi 131,072 int — ditto
#define F_ML     34103296u   // ml        4x2048x12x2 f32 = 196,608
#define F_NRM    34299904u   // dnrm      16384 f32
#define F_USED   34316288u   // used      16384 int
#define F_ROWMAP 34332672u   // rowmap    16384 int
#define F_INVMAP 34349056u   // invmap    16384 int
#define F_CNT    34365440u   // cnt       1 int
// high-water = 34,365,441 slots = 137.46 MB  (< 138.6 MB proven in R1)

typedef const __attribute__((address_space(1))) void* gptr_as1;
typedef __attribute__((address_space(3))) void* lptr_as3;
#define GLDS16(gp, lp) __builtin_amdgcn_global_load_lds((gptr_as1)(gp), (lptr_as3)(lp), 16, 0, 0)

// ---------------- helpers ----------------
__device__ __forceinline__ float wavesum(float s) {
#pragma unroll
  for (int d2 = 32; d2 > 0; d2 >>= 1) s += __shfl_xor(s, d2);
  return s;
}
// Block-sum over 256 threads (k_lngate3 only).
__device__ __forceinline__ float bsum(float v, float* red) {
  int t = threadIdx.x;
  v = wavesum(v);
  if ((t & 63) == 0) red[t >> 6] = v;
  __syncthreads();
  float r = red[0] + red[1] + red[2] + red[3];
  __syncthreads();   // protect red[] (WAR) for the next call
  return r;
}

// ---------------- fused pre-pass: dict/local norms + 8 weight transposes -------
// blocks [0,4096): dict norms, wave-per-row (4 rows/block, ZERO barriers);
// [4096,4608): local raw+norm, wave-per-row; [4608,9216): wt transposes.
__global__ __launch_bounds__(256) void k_prep_wt(
    const float* __restrict__ dict, const float* __restrict__ local,
    half_t* __restrict__ gdict_h, float* __restrict__ dnrm,
    half_t* __restrict__ loc_h, half_t* __restrict__ tn_h,
    const float* w0, const float* w1, const float* w2, const float* w3,
    const float* w4, const float* w5, const float* w6, const float* w7,
    const float* b0, const float* b1, const float* b2, const float* b3,
    const float* b4, const float* b5, const float* b6, const float* b7,
    half_t* __restrict__ Wt, float* __restrict__ bfout) {
  __shared__ float tile[32][33];
  int g = blockIdx.x, t = threadIdx.x;
  int wid = t >> 6, lane = t & 63;
  if (g < 4096) {                       // dict: 4 rows/block, wave per row
    size_t r = (size_t)g * 4 + wid;
    const float4* xr = (const float4*)(dict + r * (size_t)D);
    float4 a = xr[lane], b = xr[lane + 64], c = xr[lane + 128];
    float s = a.x*a.x + a.y*a.y + a.z*a.z + a.w*a.w
            + b.x*b.x + b.y*b.y + b.z*b.z + b.w*b.w
            + c.x*c.x + c.y*c.y + c.z*c.z + c.w*c.w;
    s = wavesum(s);
    float n = sqrtf(s), inv = 1.0f / n;
    half4v* yr = (half4v*)(gdict_h + r * (size_t)D);
    half4v ha, hb, hc;
    ha[0]=(half_t)(a.x*inv); ha[1]=(half_t)(a.y*inv); ha[2]=(half_t)(a.z*inv); ha[3]=(half_t)(a.w*inv);
    hb[0]=(half_t)(b.x*inv); hb[1]=(half_t)(b.y*inv); hb[2]=(half_t)(b.z*inv); hb[3]=(half_t)(b.w*inv);
    hc[0]=(half_t)(c.x*inv); hc[1]=(half_t)(c.y*inv); hc[2]=(half_t)(c.z*inv); hc[3]=(half_t)(c.w*inv);
    yr[lane] = ha; yr[lane + 64] = hb; yr[lane + 128] = hc;
    if (lane == 0) dnrm[r] = n;
  } else if (g < 4608) {                // local: 4 rows/block, wave per row
    size_t r = (size_t)(g - 4096) * 4 + wid;
    const float4* xr = (const float4*)(local + r * (size_t)D);
    float4 a = xr[lane], b = xr[lane + 64], c = xr[lane + 128];
    float s = a.x*a.x + a.y*a.y + a.z*a.z + a.w*a.w
            + b.x*b.x + b.y*b.y + b.z*b.z + b.w*b.w
            + c.x*c.x + c.y*c.y + c.z*c.z + c.w*c.w;
    s = wavesum(s);
    float inv = 1.0f / sqrtf(s);
    half4v* rr = (half4v*)(loc_h + r * (size_t)D);
    half4v* nr = (half4v*)(tn_h + r * (size_t)D);
    half4v ra, rb, rc, na, nb, nc;
    ra[0]=(half_t)a.x; ra[1]=(half_t)a.y; ra[2]=(half_t)a.z; ra[3]=(half_t)a.w;
    rb[0]=(half_t)b.x; rb[1]=(half_t)b.y; rb[2]=(half_t)b.z; rb[3]=(half_t)b.w;
    rc[0]=(half_t)c.x; rc[1]=(half_t)c.y; rc[2]=(half_t)c.z; rc[3]=(half_t)c.w;
    na[0]=(half_t)(a.x*inv); na[1]=(half_t)(a.y*inv); na[2]=(half_t)(a.z*inv); na[3]=(half_t)(a.w*inv);
    nb[0]=(half_t)(b.x*inv); nb[1]=(half_t)(b.y*inv); nb[2]=(half_t)(b.z*inv); nb[3]=(half_t)(b.w*inv);
    nc[0]=(half_t)(c.x*inv); nc[1]=(half_t)(c.y*inv); nc[2]=(half_t)(c.z*inv); nc[3]=(half_t)(c.w*inv);
    rr[lane] = ra; rr[lane + 64] = rb; rr[lane + 128] = rc;
    nr[lane] = na; nr[lane + 64] = nb; nr[lane + 128] = nc;
  } else {
    const float* wsrcs[8] = {w0,w1,w2,w3,w4,w5,w6,w7};
    const float* bsrcs[8] = {b0,b1,b2,b3,b4,b5,b6,b7};
    int id = g - 4608;
    int z = id / 576, rem = id % 576;
    int by = rem / 24, bx = rem % 24;
    const float* Wsrc = wsrcs[z];
    half_t* dst = Wt + (size_t)z * D * D;
    int tx = t & 31, ty = t >> 5;
    int c0 = bx * 32, r0 = by * 32;
#pragma unroll
    for (int j = 0; j < 4; j++)
      tile[ty + j*8][tx] = Wsrc[(size_t)(r0 + ty + j*8) * D + c0 + tx];
    __syncthreads();
#pragma unroll
    for (int j = 0; j < 4; j++)
      dst[(size_t)(c0 + ty + j*8) * D + r0 + tx] = (half_t)tile[tx][ty + j*8];
    if (bx == 0 && by == 0) {
#pragma unroll
      for (int j = 0; j < 3; j++)
        bfout[z * D + t + j*256] = bsrcs[z][t + j*256];
    }
  }
}

// ---------------- 128x128 fp16 MFMA NT GEMM core (kept for k_gemm_wo) ----------
__device__ __forceinline__ void hgemm_core(
    const half_t* __restrict__ A, const half_t* __restrict__ B,
    const float* __restrict__ bias, const float* __restrict__ dnrm,
    const int* __restrict__ rowmap, void* __restrict__ Cout,
    int N, int K, int outHalf, int bx, int by, int mhalf,
    half_t* As, half_t* Bs) {
  int tid = threadIdx.x;
  int wid = tid >> 6, lane = tid & 63;
  int l16 = lane & 15, quad = lane >> 4;
  int n0 = bx * 128, m0 = by * 128;
  if (mhalf && m0 >= mhalf) { B += (size_t)D * D; if (bias) bias += D; }
  int wm = (wid & 1) * 64, wn = (wid >> 1) * 64;

  int r0  = tid >> 3;
  int cbg = (tid & 7) ^ (r0 & 7);
  const half_t* Aps[4];
#pragma unroll
  for (int i = 0; i < 4; i++) {
    int mm = m0 + r0 + 32*i;
    int mr = rowmap ? rowmap[mm] : mm;
    Aps[i] = A + (size_t)mr * K + cbg * 8;
  }
  const half_t* Bp = B + (size_t)(n0 + r0) * K + cbg * 8;

  floatx4 acc[4][4];
#pragma unroll
  for (int i = 0; i < 4; i++)
#pragma unroll
    for (int j = 0; j < 4; j++) { acc[i][j][0]=0.f; acc[i][j][1]=0.f; acc[i][j][2]=0.f; acc[i][j][3]=0.f; }

  for (int k0 = 0; k0 < K; k0 += 64) {
#pragma unroll
    for (int i = 0; i < 4; i++)
      GLDS16(Aps[i] + k0, As + ((size_t)i*256 + wid*64) * 8);
#pragma unroll
    for (int i = 0; i < 4; i++)
      GLDS16(Bp + k0 + (size_t)i * 32 * K, Bs + ((size_t)i*256 + wid*64) * 8);
    __syncthreads();
#pragma unroll
    for (int ks = 0; ks < 2; ks++) {
      half8 af[4], bf[4];
#pragma unroll
      for (int i = 0; i < 4; i++) {
        int row = wm + i*16 + l16;
        int cb = (quad + ks*4) ^ (row & 7);
        af[i] = *(const half8*)&As[row*64 + cb*8];
      }
#pragma unroll
      for (int j = 0; j < 4; j++) {
        int row = wn + j*16 + l16;
        int cb = (quad + ks*4) ^ (row & 7);
        bf[j] = *(const half8*)&Bs[row*64 + cb*8];
      }
#pragma unroll
      for (int i = 0; i < 4; i++)
#pragma unroll
        for (int j = 0; j < 4; j++)
          acc[i][j] = __builtin_amdgcn_mfma_f32_16x16x32_f16(af[i], bf[j], acc[i][j], 0, 0, 0);
    }
    __syncthreads();
  }

  float bcol[4];
#pragma unroll
  for (int j = 0; j < 4; j++) bcol[j] = bias ? bias[n0 + wn + j*16 + l16] : 0.f;
  if (outHalf) {
    half_t* C = (half_t*)Cout;
#pragma unroll
    for (int i = 0; i < 4; i++)
#pragma unroll
      for (int r = 0; r < 4; r++) {
        int grow = m0 + wm + i*16 + quad*4 + r;
        float sc = dnrm ? dnrm[rowmap ? rowmap[grow] : grow] : 1.0f;
#pragma unroll
        for (int j = 0; j < 4; j++)
          C[(size_t)grow * N + n0 + wn + j*16 + l16] = (half_t)(acc[i][j][r] * sc + bcol[j]);
      }
  } else {
    float* C = (float*)Cout;
#pragma unroll
    for (int i = 0; i < 4; i++)
#pragma unroll
      for (int r = 0; r < 4; r++) {
        int grow = m0 + wm + i*16 + quad*4 + r;
        float sc = dnrm ? dnrm[rowmap ? rowmap[grow] : grow] : 1.0f;
#pragma unroll
        for (int j = 0; j < 4; j++)
          C[(size_t)grow * N + n0 + wn + j*16 + l16] = acc[i][j][r] * sc + bcol[j];
      }
  }
}

// ---------------- 256x256 8-wave double-buffered fp16 NT GEMM core -------------
// R6-proven 2-phase template (beats the 4-phase counted-vmcnt variant: 75 vs
// 84.5 µs, R6/R7 A/B). Per K-tile: issue next tile's 8 global_load_lds, 64
// MFMAs from current buffer, one __syncthreads.
__device__ __forceinline__ void hgemm256_core(
    const half_t* __restrict__ A, const half_t* __restrict__ B,
    const float* __restrict__ bias, const float* __restrict__ dnrm,
    const int* __restrict__ rowmap, half_t* __restrict__ C,
    int N, int K, int bx, int by,
    half_t* As0, half_t* As1, half_t* Bs0, half_t* Bs1) {
  const int tid = threadIdx.x;
  const int wid = tid >> 6, lane = tid & 63;
  const int l16 = lane & 15, quad = lane >> 4;
  const int m0 = by * 256, n0 = bx * 256;

  const int r0 = tid >> 3;                    // [0,64)
  const int cg = (tid & 7) ^ (r0 & 7);        // (i*64)&7 == 0, same for all i
  const half_t* Aps[4]; const half_t* Bps[4];
#pragma unroll
  for (int i = 0; i < 4; i++) {
    int mm = m0 + r0 + i * 64;
    int mr = rowmap ? rowmap[mm] : mm;
    Aps[i] = A + (size_t)mr * K + cg * 8;
    Bps[i] = B + (size_t)(n0 + r0 + i * 64) * K + cg * 8;
  }

  const int arow = (wid & 3) * 32 + l16;      // row in 128-row A quadrant
  const int brow = (wid >> 2) * 64 + l16;     // row in 128-row B quadrant
  const int cb0 = (quad ^ (l16 & 7)) * 8;
  const int cb1 = ((quad + 4) ^ (l16 & 7)) * 8;

  floatx4 acc[4][2][4];                        // [quadrant][mi][ni]
#pragma unroll
  for (int q = 0; q < 4; q++)
#pragma unroll
    for (int mi = 0; mi < 2; mi++)
#pragma unroll
      for (int ni = 0; ni < 4; ni++) {
        acc[q][mi][ni][0] = 0.f; acc[q][mi][ni][1] = 0.f;
        acc[q][mi][ni][2] = 0.f; acc[q][mi][ni][3] = 0.f;
      }
  half8 af[2][2], bf[4][2];

#define STAGE(Adst, Bdst, kn) { \
    GLDS16(Aps[0] + (kn), (Adst) + (0*512 + wid*64) * 8); \
    GLDS16(Aps[1] + (kn), (Adst) + (1*512 + wid*64) * 8); \
    GLDS16(Aps[2] + (kn), (Adst) + (2*512 + wid*64) * 8); \
    GLDS16(Aps[3] + (kn), (Adst) + (3*512 + wid*64) * 8); \
    GLDS16(Bps[0] + (kn), (Bdst) + (0*512 + wid*64) * 8); \
    GLDS16(Bps[1] + (kn), (Bdst) + (1*512 + wid*64) * 8); \
    GLDS16(Bps[2] + (kn), (Bdst) + (2*512 + wid*64) * 8); \
    GLDS16(Bps[3] + (kn), (Bdst) + (3*512 + wid*64) * 8); }
#define LDA(qm) { const int rb_ = (qm)*8192 + arow*64; \
    af[0][0] = *(const half8*)&Ar[rb_ + cb0];        af[0][1] = *(const half8*)&Ar[rb_ + cb1]; \
    af[1][0] = *(const half8*)&Ar[rb_ + 1024 + cb0]; af[1][1] = *(const half8*)&Ar[rb_ + 1024 + cb1]; }
#define LDB(qn) { const int rb_ = (qn)*8192 + brow*64; \
    bf[0][0] = *(const half8*)&Br[rb_ + cb0];        bf[0][1] = *(const half8*)&Br[rb_ + cb1]; \
    bf[1][0] = *(const half8*)&Br[rb_ + 1024 + cb0]; bf[1][1] = *(const half8*)&Br[rb_ + 1024 + cb1]; \
    bf[2][0] = *(const half8*)&Br[rb_ + 2048 + cb0]; bf[2][1] = *(const half8*)&Br[rb_ + 2048 + cb1]; \
    bf[3][0] = *(const half8*)&Br[rb_ + 3072 + cb0]; bf[3][1] = *(const half8*)&Br[rb_ + 3072 + cb1]; }
#define MM(q) { _Pragma("unroll") for (int mi = 0; mi < 2; mi++) { \
    _Pragma("unroll") for (int ni = 0; ni < 4; ni++) { \
      acc[q][mi][ni] = __builtin_amdgcn_mfma_f32_16x16x32_f16(af[mi][0], bf[ni][0], acc[q][mi][ni], 0, 0, 0); \
      acc[q][mi][ni] = __builtin_amdgcn_mfma_f32_16x16x32_f16(af[mi][1], bf[ni][1], acc[q][mi][ni], 0, 0, 0); } } }

  const int NT = K >> 6;                       // 12 for K=768
  STAGE(As0, Bs0, 0);
  __syncthreads();

  half_t* Ar = As0; half_t* Aw = As1;
  half_t* Br = Bs0; half_t* Bw = Bs1;
  for (int t = 0; t < NT; ++t) {
    if (t + 1 < NT) STAGE(Aw, Bw, (t + 1) * 64);   // prefetch issued first
    LDA(0); LDB(0); MM(0);                         // Q(0,0)
    LDB(1);         MM(1);                         // Q(0,1)
    LDA(1);         MM(2);                         // Q(1,1)
    LDB(0);         MM(3);                         // Q(1,0)
    if (t + 1 < NT) __syncthreads();               // drains prefetch + reads
    half_t* tp = Ar; Ar = Aw; Aw = tp;
    tp = Br; Br = Bw; Bw = tp;
  }

  // ---- epilogue ----
  float bcol[2][4];
#pragma unroll
  for (int qn = 0; qn < 2; qn++)
#pragma unroll
    for (int ni = 0; ni < 4; ni++)
      bcol[qn][ni] = bias ? bias[n0 + qn*128 + (wid >> 2)*64 + ni*16 + l16] : 0.f;
#pragma unroll
  for (int q = 0; q < 4; q++) {
    const int qm = q >> 1;                       // 0,0,1,1
    const int qn = (q == 1 || q == 2) ? 1 : 0;   // 0,1,1,0
#pragma unroll
    for (int mi = 0; mi < 2; mi++)
#pragma unroll
      for (int r = 0; r < 4; r++) {
        int grow = m0 + qm*128 + (wid & 3)*32 + mi*16 + quad*4 + r;
        float sc = dnrm ? dnrm[rowmap ? rowmap[grow] : grow] : 1.0f;
#pragma unroll
        for (int ni = 0; ni < 4; ni++)
          C[(size_t)grow * N + n0 + qn*128 + (wid >> 2)*64 + ni*16 + l16] =
              (half_t)(acc[q][mi][ni][r] * sc + bcol[qn][ni]);
      }
  }
#undef STAGE
#undef LDA
#undef LDB
#undef MM
}

// ---------------- merged sim (512 blocks) + lp (96 blocks), 256^2 tiles -------
__global__ __launch_bounds__(512) void k_gemm_simlp(
    const half_t* __restrict__ tn, const half_t* __restrict__ gd,
    half_t* __restrict__ sim,
    const half_t* __restrict__ loc, const half_t* __restrict__ wt0,
    const float* __restrict__ bf0, half_t* __restrict__ lp) {
  __shared__ half_t As[2][256*64];
  __shared__ half_t Bs[2][256*64];
  int gid = blockIdx.x;
  int swz = (gid & 7) * 76 + (gid >> 3);   // 608 = 8*76, bijective XCD chunking
  if (swz < 512) {       // sim: logical grid 64 x 8, 8x8 panel swizzle
    int bx = (swz & 7) + ((swz >> 3) >> 3) * 8;
    int by = (swz >> 3) & 7;
    hgemm256_core(tn, gd, nullptr, nullptr, nullptr, sim, NDICT, D, bx, by,
                  As[0], As[1], Bs[0], Bs[1]);
  } else {               // lp: logical grid 12 x 8
    int rel = swz - 512;
    int bx = rel >> 3;
    int by = rel & 7;
    hgemm256_core(loc, wt0, bf0, nullptr, nullptr, lp, 3072, D, bx, by,
                  As[0], As[1], Bs[0], Bs[1]);
  }
}

// ---------------- dkv over compacted dict rows (early exit past count) ---------
__global__ __launch_bounds__(512) void k_gemm_dkv(
    const half_t* __restrict__ gd, const half_t* __restrict__ wt4,
    const float* __restrict__ bf4, const float* __restrict__ dnrm,
    const int* __restrict__ rowmap, const int* __restrict__ cnt,
    half_t* __restrict__ dkv) {
  __shared__ half_t As[2][256*64];
  __shared__ half_t Bs[2][256*64];
  int mceil = (*cnt + 255) & ~255;
  if ((int)blockIdx.y * 256 >= mceil) return;
  hgemm256_core(gd, wt4, bf4, dnrm, rowmap, dkv, 1536, D,
                blockIdx.x, blockIdx.y, As[0], As[1], Bs[0], Bs[1]);
}

// ---------------- fused output projection (ll|lg via mhalf), fp32 out ----------
__global__ __launch_bounds__(256) void k_gemm_wo(
    const half_t* __restrict__ ctx, const half_t* __restrict__ wt6,
    const float* __restrict__ bf6, float* __restrict__ dd) {
  __shared__ half_t As[128*64];
  __shared__ half_t Bs[128*64];
  hgemm_core(ctx, wt6, bf6, nullptr, nullptr, dd, D, D, 0, blockIdx.x, blockIdx.y, MROWS, As, Bs);
}

// ---------------- top-k stage 1: tournament argmax, wave per (row, segment) ----
__global__ __launch_bounds__(256) void k_topk1(const half_t* __restrict__ sim,
                                               float* __restrict__ candv,
                                               int* __restrict__ candi,
                                               int* __restrict__ used,
                                               int* __restrict__ rowmap,
                                               int* __restrict__ cnt) {
  int t = threadIdx.x;
  if (t < 4) used[blockIdx.x * 4 + t] = 0;
  else if (t < 8) rowmap[blockIdx.x * 4 + t - 4] = 0;
  if (blockIdx.x == 0 && t == 8) *cnt = 0;

  int gw = blockIdx.x * 4 + (t >> 6);
  int lane = t & 63;
  int row = gw >> 3, seg = gw & 7;
  int cbase = seg * 2048;
  const half_t* p = sim + (size_t)row * NDICT + cbase;

  float v[32];
#pragma unroll
  for (int i = 0; i < 4; i++) {
    half8 h = *(const half8*)(p + i*512 + lane*8);
#pragma unroll
    for (int j = 0; j < 8; j++) v[i*8 + j] = (float)h[j];
  }
  float m = v[0]; int pos = 0;
#pragma unroll
  for (int i = 1; i < 32; i++) { if (v[i] > m) { m = v[i]; pos = i; } }

  for (int it = 0; it < 8; it++) {
    int gidx = cbase + (pos >> 3) * 512 + lane * 8 + (pos & 7);
    float bv = m; int bi = gidx;
#pragma unroll
    for (int d2 = 1; d2 < 64; d2 <<= 1) {
      float ov = __shfl_xor(bv, d2); int oi = __shfl_xor(bi, d2);
      if (ov > bv || (ov == bv && oi < bi)) { bv = ov; bi = oi; }
    }
    if (lane == 0) {
      size_t base = (size_t)row * 64 + seg * 8 + it;
      candv[base] = bv; candi[base] = bi;
    }
    if (bi == gidx) {
      v[pos] = -INFINITY;
      m = v[0]; pos = 0;
#pragma unroll
      for (int i = 1; i < 32; i++) { if (v[i] > m) { m = v[i]; pos = i; } }
    }
  }
}

// ---------------- top-k stage 2: wave per row over 64 candidates ----------------
// (k_mark fused in: lane0 marks used[] while emitting topi)
__global__ __launch_bounds__(256) void k_topk2(const float* __restrict__ candv,
                                               const int* __restrict__ candi,
                                               int* __restrict__ topi,
                                               int* __restrict__ used) {
  int row = blockIdx.x * 4 + (threadIdx.x >> 6);
  int lane = threadIdx.x & 63;
  float v = candv[(size_t)row * 64 + lane];
  int id = candi[(size_t)row * 64 + lane];
#pragma unroll
  for (int it = 0; it < 8; it++) {
    float bv = v; int bi = id;
#pragma unroll
    for (int d2 = 1; d2 < 64; d2 <<= 1) {
      float ov = __shfl_xor(bv, d2); int oi = __shfl_xor(bi, d2);
      if (ov > bv || (ov == bv && oi < bi)) { bv = ov; bi = oi; }
    }
    if (lane == 0) { topi[row * 8 + it] = bi; used[bi] = 1; }
    if (id == bi) { v = -INFINITY; id = 0x7FFFFFFF; }
  }
}

// ---------------- dedup: compact used dict rows (remap folded into flash2) -----
__global__ __launch_bounds__(256) void k_cmp(const int* __restrict__ used,
                                             int* __restrict__ rowmap,
                                             int* __restrict__ invmap,
                                             int* __restrict__ cnt) {
  int i = blockIdx.x * 256 + threadIdx.x;
  if (used[i]) { int s = atomicAdd(cnt, 1); rowmap[s] = i; invmap[i] = s; }
}

// ---------------- combined fp16 MFMA flash: lg (K-split ns=4) + ll (ns=1) ------
// lg gathers via invmap[topi[...]] (k_remap launch folded in).
__global__ __launch_bounds__(256) void k_flash2(
    const half_t* __restrict__ lp, const half_t* __restrict__ dkv,
    const int* __restrict__ topi_, const int* __restrict__ invmap,
    half_t* __restrict__ ctx_ll, half_t* __restrict__ Opart, float* __restrict__ ml) {
  __shared__ half_t Ks[64][72];
  __shared__ half_t Vt[64][72];
  __shared__ half_t Ps[4][16][72];

  int tid = threadIdx.x;
  int wid = tid >> 6;
  int lane = tid & 63;
  int l16 = lane & 15, quad = lane >> 4;

  const half_t *Q, *K, *V; const int* kidx; half_t* Out;
  int qS, kvS, Sk, ns, rel;
  if (blockIdx.x < BATCH*HEADS*4*4) {     // lg
    rel = blockIdx.x;
    Q = lp + 2304; qS = 3072; K = dkv; V = dkv + 768; kvS = 1536;
    kidx = topi_; Sk = LSEQ*TOPK; ns = 4; Out = nullptr;
  } else {                                 // ll
    rel = blockIdx.x - BATCH*HEADS*4*4;
    Q = lp; qS = 3072; K = lp + 768; V = lp + 1536; kvS = 3072;
    kidx = nullptr; Sk = LSEQ; ns = 1; Out = ctx_ll;
  }

  int sp = rel % ns;
  int rest = rel / ns;
  int qt = rest & 3;
  int h  = (rest >> 2) % HEADS;
  int bb = rest / (4 * HEADS);
  int q0 = qt * 64 + wid * 16;
  int sLen = Sk / ns, s0 = sp * sLen;

  const float SCL = 0.125f * 1.4426950408889634f;
  const half_t* qrow = Q + (size_t)(bb * LSEQ + q0 + l16) * qS + h * DH;
  half8 aq0 = *(const half8*)(qrow + quad*8);
  half8 aq1 = *(const half8*)(qrow + 32 + quad*8);

  floatx4 o[4];
#pragma unroll
  for (int nt = 0; nt < 4; nt++) { o[nt][0]=0.f; o[nt][1]=0.f; o[nt][2]=0.f; o[nt][3]=0.f; }
  float mreg[4] = {-INFINITY, -INFINITY, -INFINITY, -INFINITY};
  float lreg[4] = {0.f, 0.f, 0.f, 0.f};

  for (int k0 = s0; k0 < s0 + sLen; k0 += 64) {
    {
      int row = tid >> 2, cg = tid & 3;
      int key = k0 + row;
      size_t rowid = kidx ? (size_t)invmap[kidx[(size_t)bb * Sk + key]]
                          : (size_t)(bb * LSEQ + key);
      const half_t* kb = K + rowid * (size_t)kvS + h * DH + cg * 16;
      const half_t* vb = V + rowid * (size_t)kvS + h * DH + cg * 16;
      *(half8*)&Ks[row][cg*16]     = *(const half8*)kb;
      *(half8*)&Ks[row][cg*16 + 8] = *(const half8*)(kb + 8);
      half8 v0 = *(const half8*)vb, v1 = *(const half8*)(vb + 8);
#pragma unroll
      for (int jj = 0; jj < 8; jj++) { Vt[cg*16 + jj][row] = v0[jj]; Vt[cg*16 + 8 + jj][row] = v1[jj]; }
    }
    __syncthreads();

    floatx4 c[4];
#pragma unroll
    for (int nt = 0; nt < 4; nt++) {
      half8 b0 = *(const half8*)&Ks[nt*16 + l16][quad*8];
      half8 b1 = *(const half8*)&Ks[nt*16 + l16][32 + quad*8];
      floatx4 z; z[0]=0.f; z[1]=0.f; z[2]=0.f; z[3]=0.f;
      z = __builtin_amdgcn_mfma_f32_16x16x32_f16(aq0, b0, z, 0, 0, 0);
      z = __builtin_amdgcn_mfma_f32_16x16x32_f16(aq1, b1, z, 0, 0, 0);
      c[nt] = z;
    }

    float alpha[4];
#pragma unroll
    for (int r = 0; r < 4; r++) {
      float mx = fmaxf(fmaxf(c[0][r], c[1][r]), fmaxf(c[2][r], c[3][r]));
      mx = fmaxf(mx, __shfl_xor(mx, 1));
      mx = fmaxf(mx, __shfl_xor(mx, 2));
      mx = fmaxf(mx, __shfl_xor(mx, 4));
      mx = fmaxf(mx, __shfl_xor(mx, 8));
      float mn = fmaxf(mreg[r], mx);
      float al = __builtin_amdgcn_exp2f((mreg[r] - mn) * SCL);
      float ps = 0.f;
#pragma unroll
      for (int nt = 0; nt < 4; nt++) {
        float p = __builtin_amdgcn_exp2f((c[nt][r] - mn) * SCL);
        c[nt][r] = p; ps += p;
      }
      ps += __shfl_xor(ps, 1);
      ps += __shfl_xor(ps, 2);
      ps += __shfl_xor(ps, 4);
      ps += __shfl_xor(ps, 8);
      mreg[r] = mn; lreg[r] = lreg[r] * al + ps; alpha[r] = al;
    }

#pragma unroll
    for (int nt = 0; nt < 4; nt++)
#pragma unroll
      for (int r = 0; r < 4; r++)
        Ps[wid][quad*4 + r][nt*16 + l16] = (half_t)c[nt][r];
    half8 p0 = *(const half8*)&Ps[wid][l16][quad*8];
    half8 p1 = *(const half8*)&Ps[wid][l16][32 + quad*8];

#pragma unroll
    for (int nt = 0; nt < 4; nt++)
#pragma unroll
      for (int r = 0; r < 4; r++) o[nt][r] *= alpha[r];
#pragma unroll
    for (int nt = 0; nt < 4; nt++) {
      half8 v0 = *(const half8*)&Vt[nt*16 + l16][quad*8];
      half8 v1 = *(const half8*)&Vt[nt*16 + l16][32 + quad*8];
      o[nt] = __builtin_amdgcn_mfma_f32_16x16x32_f16(p0, v0, o[nt], 0, 0, 0);
      o[nt] = __builtin_amdgcn_mfma_f32_16x16x32_f16(p1, v1, o[nt], 0, 0, 0);
    }
    __syncthreads();
  }

  if (ns == 1) {
    half_t* ob = Out + (size_t)(bb * LSEQ + q0 + quad*4) * D + h * DH;
#pragma unroll
    for (int r = 0; r < 4; r++) {
      float inv = 1.0f / lreg[r];
#pragma unroll
      for (int nt = 0; nt < 4; nt++)
        ob[(size_t)r * D + nt*16 + l16] = (half_t)(o[nt][r] * inv);
    }
  } else {
    size_t rbase = (size_t)sp * MROWS + bb * LSEQ + q0 + quad*4;
    half_t* ob = Opart + rbase * D + h * DH;
#pragma unroll
    for (int r = 0; r < 4; r++) {
      float inv = 1.0f / lreg[r];
#pragma unroll
      for (int nt = 0; nt < 4; nt++)
        ob[(size_t)r * D + nt*16 + l16] = (half_t)(o[nt][r] * inv);
    }
    if (l16 == 0) {
#pragma unroll
      for (int r = 0; r < 4; r++) {
        size_t mi = ((rbase + r) * HEADS + h) * 2;
        ml[mi] = mreg[r]; ml[mi + 1] = lreg[r];
      }
    }
  }
}

// ---------------- combine K-split partials (in-place: ctx == Opart s0) ---------
__global__ __launch_bounds__(256) void k_comb(const half_t* __restrict__ Op,
                                              const float* __restrict__ ml,
                                              half_t* __restrict__ ctx) {
  int r = blockIdx.x, t = threadIdx.x;
  const float SCL = 0.125f * 1.4426950408889634f;
#pragma unroll
  for (int i = 0; i < 3; i++) {
    int col = t + i*256;
    int h = col >> 6;
    float m[4], l[4];
    float ms = -INFINITY;
#pragma unroll
    for (int s = 0; s < 4; s++) {
      size_t mi = (((size_t)s * MROWS + r) * HEADS + h) * 2;
      m[s] = ml[mi]; l[s] = ml[mi + 1];
      ms = fmaxf(ms, m[s]);
    }
    float den = 0.f, num = 0.f;
#pragma unroll
    for (int s = 0; s < 4; s++) {
      float w = __builtin_amdgcn_exp2f((m[s] - ms) * SCL) * l[s];
      den += w;
      num += w * (float)Op[((size_t)s * MROWS + r) * D + col];
    }
    ctx[(size_t)r * D + col] = (half_t)(num / den);
  }
}

// ---------------- fused tail: LN(ll+loc), LN(lg+loc), LN(sum), sigmoid gate ----
__global__ __launch_bounds__(256) void k_lngate3(
    const float* __restrict__ dd, const float* __restrict__ loc,
    const float* __restrict__ llg, const float* __restrict__ llb,
    const float* __restrict__ lgg, const float* __restrict__ lgb,
    const float* __restrict__ lng, const float* __restrict__ lnb,
    const float* __restrict__ aw, const float* __restrict__ ow,
    const float* __restrict__ ab, const float* __restrict__ orb,
    float* __restrict__ y) {
  __shared__ float red[8];
  size_t r = blockIdx.x; int t = threadIdx.x;
  const float* ar = dd + r*(size_t)D;                    // ll dense
  const float* br = dd + ((size_t)MROWS + r)*(size_t)D;  // lg dense
  const float* lcl = loc + r*(size_t)D;
  float l0 = lcl[t], l1 = lcl[t+256], l2 = lcl[t+512];

  float a0 = ar[t]+l0, a1 = ar[t+256]+l1, a2 = ar[t+512]+l2;
  float mu = bsum(a0+a1+a2, red) * (1.0f/768.0f);
  float d0 = a0-mu, d1 = a1-mu, d2 = a2-mu;
  float var = bsum(d0*d0 + d1*d1 + d2*d2, red) * (1.0f/768.0f);
  float rstd = rsqrtf(var + 1e-12f);
  float x0 = d0*rstd*llg[t]     + llb[t];
  float x1 = d1*rstd*llg[t+256] + llb[t+256];
  float x2 = d2*rstd*llg[t+512] + llb[t+512];

  float b0 = br[t]+l0, b1 = br[t+256]+l1, b2 = br[t+512]+l2;
  mu = bsum(b0+b1+b2, red) * (1.0f/768.0f);
  d0 = b0-mu; d1 = b1-mu; d2 = b2-mu;
  var = bsum(d0*d0 + d1*d1 + d2*d2, red) * (1.0f/768.0f);
  rstd = rsqrtf(var + 1e-12f);
  x0 += d0*rstd*lgg[t]     + lgb[t];
  x1 += d1*rstd*lgg[t+256] + lgb[t+256];
  x2 += d2*rstd*lgg[t+512] + lgb[t+512];

  mu = bsum(x0+x1+x2, red) * (1.0f/768.0f);
  d0 = x0-mu; d1 = x1-mu; d2 = x2-mu;
  var = bsum(d0*d0 + d1*d1 + d2*d2, red) * (1.0f/768.0f);
  rstd = rsqrtf(var + 1e-12f);
  float o0 = d0*rstd*lng[t]     + lnb[t];
  float o1 = d1*rstd*lng[t+256] + lnb[t+256];
  float o2 = d2*rstd*lng[t+512] + lnb[t+512];

  float s = o0*aw[t] + l0*ow[t]
          + o1*aw[t+256] + l1*ow[t+256]
          + o2*aw[t+512] + l2*ow[t+512];
  float z = bsum(s, red) + ab[0] + orb[0];
  float w = 1.0f / (1.0f + __expf(-z));
  float* yr = y + r*(size_t)D;
  yr[t]     = w*o0 + (1.f-w)*l0;
  yr[t+256] = w*o1 + (1.f-w)*l1;
  yr[t+512] = w*o2 + (1.f-w)*l2;
}

extern "C" void kernel_launch(void* const* d_in, const int* in_sizes, int n_in,
                              void* d_out, int out_size, void* d_ws, size_t ws_size,
                              hipStream_t stream) {
  (void)in_sizes; (void)n_in; (void)out_size; (void)ws_size;
  const float* local = (const float*)d_in[0];
  const float* dict  = (const float*)d_in[1];
  const float* ll_g  = (const float*)d_in[10];
  const float* ll_b  = (const float*)d_in[11];
  const float* lg_g  = (const float*)d_in[20];
  const float* lg_b  = (const float*)d_in[21];
  const float* ln_g  = (const float*)d_in[22];
  const float* ln_b  = (const float*)d_in[23];
  const float* aug_w = (const float*)d_in[24];
  const float* ori_w = (const float*)d_in[25];
  const float* aug_b = (const float*)d_in[26];
  const float* ori_b = (const float*)d_in[27];

  float* W = (float*)d_ws;
  half_t* gdict_h = (half_t*)(W + F_DICT);
  half_t* tn_h    = (half_t*)(W + F_TN);
  half_t* loc_h   = (half_t*)(W + F_LOC);
  half_t* wt      = (half_t*)(W + F_WT);
  float*  bf      = W + F_BF;
  int*    topi    = (int*)(W + F_TOPI);
  half_t* lp      = (half_t*)(W + F_LP);
  half_t* sim_h   = (half_t*)(W + F_SIM);    // dead after topk1
  half_t* dkv     = (half_t*)(W + F_SIM);    // reuses sim region (serial)
  float*  dd      = W + F_SIM;               // reuses dkv region (serial)
  half_t* ctx_ll  = (half_t*)(W + F_CTX);
  half_t* ctx_lg  = (half_t*)(W + F_D1);     // = Opart s0 (in-place combine)
  half_t* Opart   = (half_t*)(W + F_D1);
  float*  candv   = W + F_CANDV;             // reuses Opart s0 (dead before flash2)
  int*    candi   = (int*)(W + F_CANDI);
  float*  ml      = W + F_ML;
  float*  dnrm    = W + F_NRM;
  int*    used    = (int*)(W + F_USED);
  int*    rowmap  = (int*)(W + F_ROWMAP);
  int*    invmap  = (int*)(W + F_INVMAP);
  int*    cnt     = (int*)(W + F_CNT);

  dim3 blk(256);
  dim3 blk5(512);
  const size_t WS = (size_t)D * D;

  // --- fused pre-pass: wave-per-row norms + weight transposes + bias concat ---
  k_prep_wt<<<4096 + 512 + 4608, blk, 0, stream>>>(
      dict, local, gdict_h, dnrm, loc_h, tn_h,
      (const float*)d_in[2], (const float*)d_in[3], (const float*)d_in[4],
      (const float*)d_in[12], (const float*)d_in[13], (const float*)d_in[14],
      (const float*)d_in[5], (const float*)d_in[15],
      (const float*)d_in[6], (const float*)d_in[7], (const float*)d_in[8],
      (const float*)d_in[16], (const float*)d_in[17], (const float*)d_in[18],
      (const float*)d_in[9], (const float*)d_in[19], wt, bf);

  // --- sim + lp in one launch (256^2 8-wave double-buffered core) ---
  k_gemm_simlp<<<512 + 96, blk5, 0, stream>>>(tn_h, gdict_h, sim_h,
                                              loc_h, wt + 0*WS, bf + 0, lp);

  // --- two-stage top-8 + dict dedup (mark fused in topk2; remap in flash2) ---
  k_topk1<<<MROWS*8/4, blk, 0, stream>>>(sim_h, candv, candi, used, rowmap, cnt);
  k_topk2<<<MROWS/4, blk, 0, stream>>>(candv, candi, topi, used);
  k_cmp<<<64, blk, 0, stream>>>(used, rowmap, invmap, cnt);

  // --- dkv over compact dict rows (dict @ w = diag(||d||) * (dnorm @ w)) ---
  k_gemm_dkv<<<dim3(6, 64), blk5, 0, stream>>>(
      gdict_h, wt + 4*WS, bf + 3072, dnrm, rowmap, cnt, dkv);

  // --- combined flash: lg (ns=4 gather via invmap[topi]) + ll (self) ---
  k_flash2<<<dim3(BATCH*HEADS*4*4 + BATCH*HEADS*4), blk, 0, stream>>>(
      lp, dkv, topi, invmap, ctx_ll, Opart, ml);
  k_comb<<<MROWS, blk, 0, stream>>>(Opart, ml, ctx_lg);

  // --- fused output projection: [ctx_ll; ctx_lg] @ {wt6|wt7} -> dd fp32 ---
  k_gemm_wo<<<dim3(6, 32), blk, 0, stream>>>(ctx_ll, wt + 6*WS, bf + 4608, dd);

  // --- fused 3-LN + gate tail ---
  k_lngate3<<<MROWS, blk, 0, stream>>>(dd, local,
      ll_g, ll_b, lg_g, lg_b, ln_g, ln_b,
      aug_w, ori_w, aug_b, ori_b, (float*)d_out);
}